// Round 3
// baseline (235.250 us; speedup 1.0000x reference)
//
#include <hip/hip_runtime.h>

// Laplacian stencil with wraparound (roll-based double gradient):
//   gx[h][w] = x[h-2][w] - 2*x[h-1][w] + x[h][w]   (h indices mod 1024)
//   gy[h][w] = x[h][w-2] - 2*x[h][w-1] + x[h][w]   (w indices mod 1024)
//   out = clip(gx + gy, -1, 1) * 0.5
// Input x: (32, 1, 1024, 1024) float32. Output same shape/dtype.

#define HH 1024
#define WW 1024

__device__ __forceinline__ float rn1(float v) {
    // remove_nan(v, 1.0)
    return (v != v) ? 1.0f : v;
}

__global__ __launch_bounds__(256) void laplacian_kernel(
        const float* __restrict__ x, float* __restrict__ out, int total4) {
    const int stride = gridDim.x * blockDim.x;
    for (int i = blockIdx.x * blockDim.x + threadIdx.x; i < total4; i += stride) {
        const int w4 = i & (WW / 4 - 1);        // which float4 within the row
        const int r  = i >> 8;                  // global row index (32*1024 rows)
        const int h  = r & (HH - 1);            // row within image
        const int imgBase = (r - h) << 10;      // image base offset in floats
        const float* __restrict__ img = x + imgBase;

        const int w     = w4 << 2;
        const int rowH  = h << 10;
        const int rowM1 = ((h - 1) & (HH - 1)) << 10;
        const int rowM2 = ((h - 2) & (HH - 1)) << 10;

        const float4 cur = *(const float4*)(img + rowH  + w);
        const float4 u1  = *(const float4*)(img + rowM1 + w);
        const float4 u2  = *(const float4*)(img + rowM2 + w);
        const float swm1 = img[rowH + ((w - 1) & (WW - 1))];
        const float swm2 = img[rowH + ((w - 2) & (WW - 1))];

        // remove_nan(x, 1.0) on every consumed element
        const float c[6] = { rn1(swm2), rn1(swm1),
                             rn1(cur.x), rn1(cur.y), rn1(cur.z), rn1(cur.w) };
        const float a1[4] = { rn1(u1.x), rn1(u1.y), rn1(u1.z), rn1(u1.w) };
        const float a2[4] = { rn1(u2.x), rn1(u2.y), rn1(u2.z), rn1(u2.w) };

        float4 o;
        float* op = &o.x;
        #pragma unroll
        for (int j = 0; j < 4; ++j) {
            const float gx = a2[j] - 2.0f * a1[j] + c[j + 2];
            const float gy = c[j]  - 2.0f * c[j + 1] + c[j + 2];
            float g = gx + gy;
            g = fminf(fmaxf(g, -1.0f), 1.0f) * 0.5f;
            op[j] = (g != g) ? 0.0f : g;        // remove_nan(g, 0.0)
        }
        *(float4*)(out + imgBase + rowH + w) = o;
    }
}

extern "C" void kernel_launch(void* const* d_in, const int* in_sizes, int n_in,
                              void* d_out, int out_size, void* d_ws, size_t ws_size,
                              hipStream_t stream) {
    const float* x = (const float*)d_in[0];
    float* out = (float*)d_out;
    const int total4 = out_size / 4;            // 8,388,608 float4s
    const int threads = 256;
    const int blocks = 2048;                    // 8 blocks/CU * 256 CUs; grid-stride
    laplacian_kernel<<<blocks, threads, 0, stream>>>(x, out, total4);
}